// Round 1
// baseline (3008.776 us; speedup 1.0000x reference)
//
#include <hip/hip_runtime.h>

// Fused: grouped conv3x3x3 (q,k,v) -> per-location attention over depth B=5 ->
// grouped 1x1x1 proj. One thread handles one (batch, head, y, x).
//
// This revision restructures the conv loads so each is a single
// global_load_dword with a uniform SGPR base (per ic,d plane), a per-lane
// 32-bit voffset (per dx column, 3 regs) and the dy tap in the signed 13-bit
// immediate ((dy-1)*512 bytes). Boundary rows are handled by a SCALAR branch
// (py is wave-uniform via readfirstlane); x edges by clamp + 0/1 mask mul on
// the 6 non-center taps only.

#define WD   128
#define HWs  (128 * 128)
#define BD   5
#define CS   (BD * HWs)   // channel stride = 81920

template<bool EDGE>
__device__ __forceinline__ void tca_body(
    int bi, int hd, int px, int py,
    const float* __restrict__ x, const float* __restrict__ last,
    const float* __restrict__ wq, const float* __restrict__ wk,
    const float* __restrict__ wv, const float* __restrict__ wp,
    float* __restrict__ out)
{
    const int ch0     = hd << 3;                    // input channel base (8 ch)
    const int base_in = (bi * 64 + ch0) * CS;       // uniform

    // ---- per-lane spatial tap offsets ----
    // interior: voffset spc[dx] (3 regs) + (dy-1)*WD folded into imm
    // edge:     fully clamped per-tap offset + combined 0/1 mask
    int   spc[3];  float xm[3];
#pragma unroll
    for (int dx = 0; dx < 3; ++dx) {
        const int xx = px + dx - 1;
        const int xc = xx < 0 ? 0 : (xx > 127 ? 127 : xx);
        spc[dx] = py * WD + xc;
        xm[dx]  = ((unsigned)xx < 128u) ? 1.f : 0.f;
    }

    int sp9[9]; float mk9[9];
    if (EDGE) {
#pragma unroll
        for (int dy = 0; dy < 3; ++dy) {
            const int yy  = py + dy - 1;
            const int yc  = yy < 0 ? 0 : (yy > 127 ? 127 : yy);
            const float ym = ((unsigned)yy < 128u) ? 1.f : 0.f;
#pragma unroll
            for (int dx = 0; dx < 3; ++dx) {
                sp9[dy * 3 + dx] = spc[dx] + (yc - py) * WD;
                mk9[dy * 3 + dx] = ym * xm[dx];
            }
        }
    }

    float q[4][BD], k[4][BD], v[4][BD];
#pragma unroll
    for (int c = 0; c < 4; ++c)
#pragma unroll
        for (int i = 0; i < BD; ++i) { q[c][i] = 0.f; k[c][i] = 0.f; v[c][i] = 0.f; }

    // ---------- pass 1: q = conv3x3x3(x, wq) ----------
#pragma unroll
    for (int ic = 0; ic < 8; ++ic) {
        const int c = ic >> 1;
        const float* __restrict__ wr = wq + hd * 216 + ic * 27;   // uniform -> s_load
#pragma unroll
        for (int d = 0; d < BD; ++d) {
            const float* __restrict__ bp = x + (base_in + ic * CS + d * HWs); // uniform SGPR base
            float t[9];
            if (EDGE) {
#pragma unroll
                for (int tp = 0; tp < 9; ++tp)
                    t[tp] = bp[sp9[tp]] * mk9[tp];
            } else {
#pragma unroll
                for (int dy = 0; dy < 3; ++dy)
#pragma unroll
                    for (int dx = 0; dx < 3; ++dx) {
                        float val = bp[spc[dx] + (dy - 1) * WD];  // imm offset ±512B
                        if (dx != 1) val *= xm[dx];               // x-edge lanes only
                        t[dy * 3 + dx] = val;
                    }
            }
#pragma unroll
            for (int dz = 0; dz < 3; ++dz) {
                const int i = d - dz + 1;                          // compile-time
                if (0 <= i && i < BD) {
#pragma unroll
                    for (int tp = 0; tp < 9; ++tp)
                        q[c][i] = fmaf(wr[dz * 9 + tp], t[tp], q[c][i]);
                }
            }
        }
    }

    // ---------- pass 2: k,v = conv3x3x3(last, wk/wv) ----------
#pragma unroll
    for (int ic = 0; ic < 8; ++ic) {
        const int c = ic >> 1;
        const float* __restrict__ wrk = wk + hd * 216 + ic * 27;
        const float* __restrict__ wrv = wv + hd * 216 + ic * 27;
#pragma unroll
        for (int d = 0; d < BD; ++d) {
            const float* __restrict__ bp = last + (base_in + ic * CS + d * HWs);
            float t[9];
            if (EDGE) {
#pragma unroll
                for (int tp = 0; tp < 9; ++tp)
                    t[tp] = bp[sp9[tp]] * mk9[tp];
            } else {
#pragma unroll
                for (int dy = 0; dy < 3; ++dy)
#pragma unroll
                    for (int dx = 0; dx < 3; ++dx) {
                        float val = bp[spc[dx] + (dy - 1) * WD];
                        if (dx != 1) val *= xm[dx];
                        t[dy * 3 + dx] = val;
                    }
            }
#pragma unroll
            for (int dz = 0; dz < 3; ++dz) {
                const int i = d - dz + 1;
                if (0 <= i && i < BD) {
#pragma unroll
                    for (int tp = 0; tp < 9; ++tp) {
                        k[c][i] = fmaf(wrk[dz * 9 + tp], t[tp], k[c][i]);
                        v[c][i] = fmaf(wrv[dz * 9 + tp], t[tp], v[c][i]);
                    }
                }
            }
        }
    }

    // ---------- attention: softmax_j( SCALE * q_i . k_j ) ----------
    const float SCALE = 0.35355339059327373f;   // 8^-0.5
    float p[BD][BD];
#pragma unroll
    for (int i = 0; i < BD; ++i) {
        float s[BD];
        float m = -3.0e38f;
#pragma unroll
        for (int j = 0; j < BD; ++j) {
            float t = q[0][i] * k[0][j];
            t = fmaf(q[1][i], k[1][j], t);
            t = fmaf(q[2][i], k[2][j], t);
            t = fmaf(q[3][i], k[3][j], t);
            t *= SCALE;
            s[j] = t;
            m = fmaxf(m, t);
        }
        float sum = 0.f;
#pragma unroll
        for (int j = 0; j < BD; ++j) { float e = __expf(s[j] - m); p[i][j] = e; sum += e; }
        const float r = 1.0f / sum;
#pragma unroll
        for (int j = 0; j < BD; ++j) p[i][j] *= r;
    }

    // ---------- out = attn @ v, then 1x1 grouped proj, store ----------
    const int sp0 = py * WD + px;
#pragma unroll
    for (int c = 0; c < 4; ++c) {
        const float w0 = wp[ch0 + 2 * c];
        const float w1 = wp[ch0 + 2 * c + 1];
#pragma unroll
        for (int i = 0; i < BD; ++i) {
            float o = p[i][0] * v[c][0];
            o = fmaf(p[i][1], v[c][1], o);
            o = fmaf(p[i][2], v[c][2], o);
            o = fmaf(p[i][3], v[c][3], o);
            o = fmaf(p[i][4], v[c][4], o);
            float* __restrict__ ob0 = out + (base_in + (2 * c)     * CS + i * HWs); // uniform
            float* __restrict__ ob1 = out + (base_in + (2 * c + 1) * CS + i * HWs); // uniform
            ob0[sp0] = w0 * o;
            ob1[sp0] = w1 * o;
        }
    }
}

__global__ __launch_bounds__(256, 4)
void TCA_49177375539279_kernel(const float* __restrict__ x,
                               const float* __restrict__ last,
                               const float* __restrict__ wq,
                               const float* __restrict__ wk,
                               const float* __restrict__ wv,
                               const float* __restrict__ wp,
                               float* __restrict__ out)
{
    const int z  = blockIdx.z;
    const int bi = z >> 3;          // batch 0..7
    const int hd = z & 7;           // head 0..7
    const int px = (blockIdx.x << 6) + (threadIdx.x & 63);   // 0..127 (per-lane)
    // py is identical across the 64 lanes of a wave -> force it scalar so the
    // edge/interior split is an s_cbranch, not exec-mask divergence.
    const int py = __builtin_amdgcn_readfirstlane((blockIdx.y << 2) + (threadIdx.x >> 6));

    if (py >= 1 && py <= 126)
        tca_body<false>(bi, hd, px, py, x, last, wq, wk, wv, wp, out);
    else
        tca_body<true >(bi, hd, px, py, x, last, wq, wk, wv, wp, out);
}

extern "C" void kernel_launch(void* const* d_in, const int* in_sizes, int n_in,
                              void* d_out, int out_size, void* d_ws, size_t ws_size,
                              hipStream_t stream)
{
    const float* x    = (const float*)d_in[0];
    const float* last = (const float*)d_in[1];
    const float* wq   = (const float*)d_in[2];
    const float* wk   = (const float*)d_in[3];
    const float* wv   = (const float*)d_in[4];
    const float* wp   = (const float*)d_in[5];
    float* out = (float*)d_out;

    dim3 grid(2, 32, 64);   // (w tiles of 64, h tiles of 4, batch*heads)
    dim3 block(256);
    hipLaunchKernelGGL(TCA_49177375539279_kernel, grid, block, 0, stream,
                       x, last, wq, wk, wv, wp, out);
}

// Round 2
// 2498.531 us; speedup vs baseline: 1.2042x; 1.2042x over previous
//
#include <hip/hip_runtime.h>

// Fused: grouped conv3x3x3 (q,k,v) -> per-location attention over depth B=5 ->
// grouped 1x1x1 proj. One thread handles one (batch, head, y, x).
//
// Addressing structure: each conv load is a single global_load_dword with a
// uniform SGPR base (per ic,d plane), a per-lane 32-bit voffset (per dx
// column, 3 regs) and the dy tap folded into the signed 13-bit immediate
// ((dy-1)*512 bytes). Boundary rows take a SCALAR branch (py is wave-uniform
// via readfirstlane); x edges are clamp + 0/1 mask mul on non-center taps.
//
// launch_bounds: (256, 2). DO NOT raise the second arg: (256,4) forces the
// allocator to 64 VGPRs, the ~90-reg live set spills to scratch, and HBM
// traffic becomes 7.3 GB of spill writes/reads (round-1 post-mortem: 2784 us).

#define WD   128
#define HWs  (128 * 128)
#define BD   5
#define CS   (BD * HWs)   // channel stride = 81920

template<bool EDGE>
__device__ __forceinline__ void tca_body(
    int bi, int hd, int px, int py,
    const float* __restrict__ x, const float* __restrict__ last,
    const float* __restrict__ wq, const float* __restrict__ wk,
    const float* __restrict__ wv, const float* __restrict__ wp,
    float* __restrict__ out)
{
    const int ch0     = hd << 3;                    // input channel base (8 ch)
    const int base_in = (bi * 64 + ch0) * CS;       // uniform

    // ---- per-lane spatial tap offsets ----
    int   spc[3];  float xm[3];
#pragma unroll
    for (int dx = 0; dx < 3; ++dx) {
        const int xx = px + dx - 1;
        const int xc = xx < 0 ? 0 : (xx > 127 ? 127 : xx);
        spc[dx] = py * WD + xc;
        xm[dx]  = ((unsigned)xx < 128u) ? 1.f : 0.f;
    }

    int sp9[9]; float mk9[9];
    if (EDGE) {
#pragma unroll
        for (int dy = 0; dy < 3; ++dy) {
            const int yy  = py + dy - 1;
            const int yc  = yy < 0 ? 0 : (yy > 127 ? 127 : yy);
            const float ym = ((unsigned)yy < 128u) ? 1.f : 0.f;
#pragma unroll
            for (int dx = 0; dx < 3; ++dx) {
                sp9[dy * 3 + dx] = spc[dx] + (yc - py) * WD;
                mk9[dy * 3 + dx] = ym * xm[dx];
            }
        }
    }

    float q[4][BD], k[4][BD], v[4][BD];
#pragma unroll
    for (int c = 0; c < 4; ++c)
#pragma unroll
        for (int i = 0; i < BD; ++i) { q[c][i] = 0.f; k[c][i] = 0.f; v[c][i] = 0.f; }

    // ---------- pass 1: q = conv3x3x3(x, wq) ----------
#pragma unroll
    for (int ic = 0; ic < 8; ++ic) {
        const int c = ic >> 1;
        const float* __restrict__ wr = wq + hd * 216 + ic * 27;   // uniform -> s_load
#pragma unroll
        for (int d = 0; d < BD; ++d) {
            const float* __restrict__ bp = x + (base_in + ic * CS + d * HWs); // SGPR base
            float t[9];
            if (EDGE) {
#pragma unroll
                for (int tp = 0; tp < 9; ++tp)
                    t[tp] = bp[sp9[tp]] * mk9[tp];
            } else {
#pragma unroll
                for (int dy = 0; dy < 3; ++dy)
#pragma unroll
                    for (int dx = 0; dx < 3; ++dx) {
                        float val = bp[spc[dx] + (dy - 1) * WD];  // imm offset ±512B
                        if (dx != 1) val *= xm[dx];               // x-edge lanes only
                        t[dy * 3 + dx] = val;
                    }
            }
#pragma unroll
            for (int dz = 0; dz < 3; ++dz) {
                const int i = d - dz + 1;                          // compile-time
                if (0 <= i && i < BD) {
#pragma unroll
                    for (int tp = 0; tp < 9; ++tp)
                        q[c][i] = fmaf(wr[dz * 9 + tp], t[tp], q[c][i]);
                }
            }
        }
    }

    // ---------- pass 2: k,v = conv3x3x3(last, wk/wv) ----------
#pragma unroll
    for (int ic = 0; ic < 8; ++ic) {
        const int c = ic >> 1;
        const float* __restrict__ wrk = wk + hd * 216 + ic * 27;
        const float* __restrict__ wrv = wv + hd * 216 + ic * 27;
#pragma unroll
        for (int d = 0; d < BD; ++d) {
            const float* __restrict__ bp = last + (base_in + ic * CS + d * HWs);
            float t[9];
            if (EDGE) {
#pragma unroll
                for (int tp = 0; tp < 9; ++tp)
                    t[tp] = bp[sp9[tp]] * mk9[tp];
            } else {
#pragma unroll
                for (int dy = 0; dy < 3; ++dy)
#pragma unroll
                    for (int dx = 0; dx < 3; ++dx) {
                        float val = bp[spc[dx] + (dy - 1) * WD];
                        if (dx != 1) val *= xm[dx];
                        t[dy * 3 + dx] = val;
                    }
            }
#pragma unroll
            for (int dz = 0; dz < 3; ++dz) {
                const int i = d - dz + 1;
                if (0 <= i && i < BD) {
#pragma unroll
                    for (int tp = 0; tp < 9; ++tp) {
                        k[c][i] = fmaf(wrk[dz * 9 + tp], t[tp], k[c][i]);
                        v[c][i] = fmaf(wrv[dz * 9 + tp], t[tp], v[c][i]);
                    }
                }
            }
        }
    }

    // ---------- attention: softmax_j( SCALE * q_i . k_j ) ----------
    const float SCALE = 0.35355339059327373f;   // 8^-0.5
    float p[BD][BD];
#pragma unroll
    for (int i = 0; i < BD; ++i) {
        float s[BD];
        float m = -3.0e38f;
#pragma unroll
        for (int j = 0; j < BD; ++j) {
            float t = q[0][i] * k[0][j];
            t = fmaf(q[1][i], k[1][j], t);
            t = fmaf(q[2][i], k[2][j], t);
            t = fmaf(q[3][i], k[3][j], t);
            t *= SCALE;
            s[j] = t;
            m = fmaxf(m, t);
        }
        float sum = 0.f;
#pragma unroll
        for (int j = 0; j < BD; ++j) { float e = __expf(s[j] - m); p[i][j] = e; sum += e; }
        const float r = 1.0f / sum;
#pragma unroll
        for (int j = 0; j < BD; ++j) p[i][j] *= r;
    }

    // ---------- out = attn @ v, then 1x1 grouped proj, store ----------
    const int sp0 = py * WD + px;
#pragma unroll
    for (int c = 0; c < 4; ++c) {
        const float w0 = wp[ch0 + 2 * c];
        const float w1 = wp[ch0 + 2 * c + 1];
#pragma unroll
        for (int i = 0; i < BD; ++i) {
            float o = p[i][0] * v[c][0];
            o = fmaf(p[i][1], v[c][1], o);
            o = fmaf(p[i][2], v[c][2], o);
            o = fmaf(p[i][3], v[c][3], o);
            o = fmaf(p[i][4], v[c][4], o);
            float* __restrict__ ob0 = out + (base_in + (2 * c)     * CS + i * HWs); // uniform
            float* __restrict__ ob1 = out + (base_in + (2 * c + 1) * CS + i * HWs); // uniform
            ob0[sp0] = w0 * o;
            ob1[sp0] = w1 * o;
        }
    }
}

__global__ __launch_bounds__(256, 2)
void TCA_49177375539279_kernel(const float* __restrict__ x,
                               const float* __restrict__ last,
                               const float* __restrict__ wq,
                               const float* __restrict__ wk,
                               const float* __restrict__ wv,
                               const float* __restrict__ wp,
                               float* __restrict__ out)
{
    const int z  = blockIdx.z;
    const int bi = z >> 3;          // batch 0..7
    const int hd = z & 7;           // head 0..7
    const int px = (blockIdx.x << 6) + (threadIdx.x & 63);   // 0..127 (per-lane)
    // py is identical across the 64 lanes of a wave -> force it scalar so the
    // edge/interior split is an s_cbranch, not exec-mask divergence.
    const int py = __builtin_amdgcn_readfirstlane((blockIdx.y << 2) + (threadIdx.x >> 6));

    if (py >= 1 && py <= 126)
        tca_body<false>(bi, hd, px, py, x, last, wq, wk, wv, wp, out);
    else
        tca_body<true >(bi, hd, px, py, x, last, wq, wk, wv, wp, out);
}

extern "C" void kernel_launch(void* const* d_in, const int* in_sizes, int n_in,
                              void* d_out, int out_size, void* d_ws, size_t ws_size,
                              hipStream_t stream)
{
    const float* x    = (const float*)d_in[0];
    const float* last = (const float*)d_in[1];
    const float* wq   = (const float*)d_in[2];
    const float* wk   = (const float*)d_in[3];
    const float* wv   = (const float*)d_in[4];
    const float* wp   = (const float*)d_in[5];
    float* out = (float*)d_out;

    dim3 grid(2, 32, 64);   // (w tiles of 64, h tiles of 4, batch*heads)
    dim3 block(256);
    hipLaunchKernelGGL(TCA_49177375539279_kernel, grid, block, 0, stream,
                       x, last, wq, wk, wv, wp, out);
}